// Round 9
// baseline (497.903 us; speedup 1.0000x reference)
//
#include <hip/hip_runtime.h>
#include <hip/hip_bf16.h>
#include <cmath>

#define CD 256
#define NQ 4096
#define NM 4096
#define NB 4
#define NTOT (NB*NQ)

typedef __bf16 bf16;
typedef __attribute__((ext_vector_type(8))) __bf16 bf16x8;
typedef __attribute__((ext_vector_type(4))) __bf16 bf16x4;
typedef __attribute__((ext_vector_type(4))) float f32x4;

#define MFMA(a,b,c) __builtin_amdgcn_mfma_f32_16x16x32_bf16(a,b,c,0,0,0)

// ---------------- K0: convert the four weight matrices to bf16 ----------------
__global__ __launch_bounds__(256) void cvt_w_kernel(
    const float* __restrict__ wq, const float* __restrict__ wk,
    const float* __restrict__ wv, const float* __restrict__ wm,
    bf16* __restrict__ out)
{
    int i = (blockIdx.x*256 + threadIdx.x)*4;
    const float* srcs[4] = {wq, wk, wv, wm};
    #pragma unroll
    for (int m=0;m<4;++m){
        f32x4 v = *(const f32x4*)(srcs[m]+i);
        bf16x4 o;
        #pragma unroll
        for (int e=0;e<4;++e) o[e] = (bf16)v[e];
        *(bf16x4*)(out + m*65536 + i) = o;
    }
}

// ---------------- K1: projection out = X @ W^T + b (bf16 out). GRID 1024 ----------------
template<int MODE>
__global__ __launch_bounds__(256) void proj_kernel(
    const float* __restrict__ X, const bf16* __restrict__ W,
    const float* __restrict__ bias, bf16* __restrict__ out)
{
    const int wave = threadIdx.x>>6, lane = threadIdx.x&63;
    const int lr = lane&15, lg = lane>>4;
    const int n0 = (blockIdx.x>>2)*64 + wave*16;
    const int co0 = (blockIdx.x&3)*64;

    bf16x8 xf[8];
    {
        const float* xr = X + (size_t)(n0+lr)*CD + lg*8;
        #pragma unroll
        for (int ch=0; ch<8; ++ch){
            f32x4 a = *(const f32x4*)(xr + ch*32);
            f32x4 b = *(const f32x4*)(xr + ch*32 + 4);
            bf16x8 t;
            #pragma unroll
            for (int e=0;e<4;++e){ t[e]=(bf16)a[e]; t[4+e]=(bf16)b[e]; }
            xf[ch]=t;
        }
    }
    f32x4 acc[4];
    #pragma unroll
    for (int t=0;t<4;++t) acc[t]=(f32x4){0,0,0,0};

    #pragma unroll
    for (int t=0;t<4;++t){
        const bf16* wr = W + (size_t)(co0+t*16+lr)*CD + lg*8;
        #pragma unroll
        for (int ch=0; ch<8; ++ch){
            bf16x8 wf = *(const bf16x8*)(wr + ch*32);
            if (MODE==0) acc[t] = MFMA(wf, xf[ch], acc[t]);   // D[co, n]
            else         acc[t] = MFMA(xf[ch], wf, acc[t]);   // D[n, co]
        }
    }

    if (MODE==0){
        const int n = n0 + lr;
        #pragma unroll
        for (int t=0;t<4;++t){
            int co = co0 + t*16 + 4*lg;
            bf16x4 o;
            #pragma unroll
            for (int r=0;r<4;++r) o[r] = (bf16)(acc[t][r] + bias[co+r]);
            *(bf16x4*)(out + (size_t)n*CD + co) = o;
        }
    } else {
        const int b = n0 / NM;
        const int m0 = (n0 % NM) + 4*lg;
        #pragma unroll
        for (int t=0;t<4;++t){
            int co = co0 + t*16 + lr;
            float bb = bias[co];
            bf16x4 o;
            #pragma unroll
            for (int r=0;r<4;++r) o[r] = (bf16)(acc[t][r] + bb);
            *(bf16x4*)(out + (size_t)b*CD*NM + (size_t)co*NM + m0) = o;
        }
    }
}

// ---------------- K2a: ksum partials. GRID 32 (b*8 + jc), 256 thr ----------------
__global__ __launch_bounds__(256) void ksum_kernel(
    const bf16* __restrict__ k, float* __restrict__ kpart)
{
    const int b = blockIdx.x>>3, jc = blockIdx.x&7;
    const int c = threadIdx.x;
    const bf16* kb = k + (size_t)b*NM*CD + (size_t)(jc*512)*CD;
    float s = 0.0f;
    for (int jj=0; jj<512; ++jj) s += (float)kb[(size_t)jj*CD + c];
    kpart[(b*8+jc)*256 + c] = s;
}

// ---------------- K2b: Gram partials G = K^T K. GRID 64 (b*16+ct*4+jc), 256 thr ----------------
// Block: rows c in [ct*64, ct*64+64), all 256 cols, j-chunk jc*1024..+1024.
__global__ __launch_bounds__(256) void gram_kernel(
    const bf16* __restrict__ k, float* __restrict__ gpart)
{
    __shared__ __align__(16) bf16 Kt[256][40];   // transposed 32-j tile, padded
    const int wave = threadIdx.x>>6, lane = threadIdx.x&63;
    const int lr = lane&15, lg = lane>>4;
    const int b = blockIdx.x>>4, ct = (blockIdx.x>>2)&3, jc = blockIdx.x&3;
    const bf16* kb = k + (size_t)b*NM*CD;

    f32x4 acc[16];
    #pragma unroll
    for (int t=0;t<16;++t) acc[t]=(f32x4){0,0,0,0};

    for (int it=0; it<32; ++it){
        const int j0 = jc*1024 + it*32;
        #pragma unroll
        for (int l=0;l<4;++l){
            int flat = threadIdx.x + l*256;
            int jj = flat>>5, cb = flat&31;
            bf16x8 v = *(const bf16x8*)(kb + (size_t)(j0+jj)*CD + cb*8);
            #pragma unroll
            for (int e=0;e<8;++e) Kt[cb*8+e][jj] = v[e];
        }
        __syncthreads();
        bf16x8 af = *(const bf16x8*)&Kt[ct*64 + wave*16 + lr][lg*8];
        #pragma unroll
        for (int t=0;t<16;++t){
            bf16x8 bf = *(const bf16x8*)&Kt[t*16+lr][lg*8];
            acc[t] = MFMA(af, bf, acc[t]);
        }
        __syncthreads();
    }
    #pragma unroll
    for (int t=0;t<16;++t){
        #pragma unroll
        for (int r=0;r<4;++r){
            int c  = ct*64 + wave*16 + 4*lg + r;
            int cp = t*16 + lr;
            gpart[(((size_t)jc*4 + b)*256 + c)*256 + cp] = acc[t][r];
        }
    }
}

// ---------------- K2c: reduce Gram partials -> bf16 G. GRID 1024, 256 thr ----------------
__global__ __launch_bounds__(256) void gfin_kernel(
    const float* __restrict__ gpart, bf16* __restrict__ gbf)
{
    int gid = blockIdx.x*256 + threadIdx.x;    // 262144 = 4 b x 65536
    int b = gid>>16, idx = gid&65535;
    float s = 0.0f;
    #pragma unroll
    for (int jc=0;jc<4;++jc) s += gpart[((size_t)jc*4 + b)*65536 + idx];
    gbf[(size_t)b*65536 + idx] = (bf16)s;
}

// ---------------- K2d: per-row stats via Y = Q.G, msq = rowdot(Y,Q). GRID 256 ----------------
// stats[row] = {c2 = mu*a2, a2 = rstd/16*log2e}
__global__ __launch_bounds__(256) void rowstats_kernel(
    const bf16* __restrict__ q, const bf16* __restrict__ gbf,
    const float* __restrict__ kpart, float* __restrict__ stats)
{
    __shared__ float ksum[256];
    const int wave = threadIdx.x>>6, lane = threadIdx.x&63;
    const int lr = lane&15, lg = lane>>4;
    const int n0 = blockIdx.x*64;
    const int b = n0 / NQ;
    const int row16 = n0 + wave*16;
    {
        int c = threadIdx.x;
        float s = 0.0f;
        #pragma unroll
        for (int p=0;p<8;++p) s += kpart[(b*8+p)*256 + c];
        ksum[c] = s;
    }
    __syncthreads();

    bf16x8 qf[8];
    const bf16* qr = q + (size_t)(row16+lr)*CD + lg*8;
    #pragma unroll
    for (int ch=0; ch<8; ++ch) qf[ch] = *(const bf16x8*)(qr + ch*32);

    const bf16* gb = gbf + (size_t)b*65536;
    f32x4 acc[16];
    #pragma unroll
    for (int t=0;t<16;++t) acc[t]=(f32x4){0,0,0,0};
    #pragma unroll
    for (int t=0;t<16;++t){
        #pragma unroll
        for (int ch=0; ch<8; ++ch){
            bf16x8 bf = *(const bf16x8*)&gb[(size_t)(t*16+lr)*256 + ch*32 + lg*8];
            acc[t] = MFMA(qf[ch], bf, acc[t]);   // Y[row][c'] (G symmetric)
        }
    }
    float msq[4]={0,0,0,0}, mean[4]={0,0,0,0};
    #pragma unroll
    for (int t=0;t<16;++t){
        float ks = ksum[t*16+lr];
        #pragma unroll
        for (int r=0;r<4;++r){
            float qv = (float)q[(size_t)(row16+4*lg+r)*CD + t*16+lr];
            msq[r]  = fmaf(acc[t][r], qv, msq[r]);
            mean[r] = fmaf(qv, ks, mean[r]);
        }
    }
    #pragma unroll
    for (int off=1; off<16; off<<=1){
        #pragma unroll
        for (int r=0;r<4;++r){
            msq[r]  += __shfl_xor(msq[r], off);
            mean[r] += __shfl_xor(mean[r], off);
        }
    }
    if (lr==0){
        #pragma unroll
        for (int r=0;r<4;++r){
            int row = row16 + 4*lg + r;
            float mu = mean[r]*(1.0f/NM);
            float ms = msq[r]*(1.0f/NM);
            float var = ms - mu*mu;
            float rstd = rsqrtf(fmaxf(var,0.0f) + 1e-5f);
            float a2 = rstd * (1.0f/16.0f) * 1.4426950408889634f;
            stats[row*2+0] = mu*a2;   // c2
            stats[row*2+1] = a2;
        }
    }
}

// ---------------- K3: flash pass — Q-tile 128, 8 waves, K-LDS prefetch, j-split 4 ----------------
// GRID 512 (qt*4+slice) x 512 threads. No max needed: exponent = s*a2 - c2 is bounded by 4 nats.
__global__ __launch_bounds__(512) void flash_kernel(
    const bf16* __restrict__ q, const bf16* __restrict__ k,
    const bf16* __restrict__ vt, const float* __restrict__ stats,
    bf16* __restrict__ opart, float* __restrict__ dpart)
{
    __shared__ __align__(16) bf16 K_lds[32][264];
    __shared__ __align__(16) bf16 P_lds[128][40];
    const int wave = threadIdx.x>>6, lane = threadIdx.x&63;
    const int lr = lane&15, lg = lane>>4;
    const int qt = blockIdx.x>>2, slice = blockIdx.x&3;
    const int n0 = qt*128;
    const int b = n0 / NQ;
    const bf16* kb = k  + (size_t)b*NM*CD;
    const bf16* vb = vt + (size_t)b*CD*NM + (size_t)(wave*32)*NM;  // wave's 32-col co-slice
    const int row16 = n0 + wave*16;

    bf16x8 qf[8];
    const bf16* qr = q + (size_t)(row16+lr)*CD + lg*8;
    #pragma unroll
    for (int ch=0; ch<8; ++ch) qf[ch] = *(const bf16x8*)(qr + ch*32);

    float c2r[4], a2r[4];
    #pragma unroll
    for (int r=0;r<4;++r){
        int row = row16 + 4*lg + r;
        c2r[r] = stats[row*2+0];
        a2r[r] = stats[row*2+1];
    }

    f32x4 oacc[8][2];
    #pragma unroll
    for (int rt=0;rt<8;++rt){ oacc[rt][0]=(f32x4){0,0,0,0}; oacc[rt][1]=(f32x4){0,0,0,0}; }
    float denom[4]={0,0,0,0};

    const int jbeg = slice*(NM/4);
    // prologue: load first K tile into regs
    bf16x8 kreg0, kreg1;
    {
        int f0 = threadIdx.x, f1 = threadIdx.x + 512;
        kreg0 = *(const bf16x8*)(kb + (size_t)(jbeg + (f0>>5))*CD + (f0&31)*8);
        kreg1 = *(const bf16x8*)(kb + (size_t)(jbeg + (f1>>5))*CD + (f1&31)*8);
    }
    for (int it=0; it<32; ++it){
        const int j0 = jbeg + it*32;
        {   // write staged tile
            int f0 = threadIdx.x, f1 = threadIdx.x + 512;
            *(bf16x8*)&K_lds[f0>>5][(f0&31)*8] = kreg0;
            *(bf16x8*)&K_lds[f1>>5][(f1&31)*8] = kreg1;
        }
        __syncthreads();
        if (it < 31){   // prefetch next tile (overlaps QK+PV)
            int f0 = threadIdx.x, f1 = threadIdx.x + 512;
            kreg0 = *(const bf16x8*)(kb + (size_t)(j0+32 + (f0>>5))*CD + (f0&31)*8);
            kreg1 = *(const bf16x8*)(kb + (size_t)(j0+32 + (f1>>5))*CD + (f1&31)*8);
        }
        // ---- QK: wave's 16 rows x 32 j ----
        f32x4 s0=(f32x4){0,0,0,0}, s1=(f32x4){0,0,0,0};
        #pragma unroll
        for (int ch=0; ch<8; ++ch){
            s0 = MFMA(qf[ch], *(const bf16x8*)&K_lds[lr][lg*8+ch*32], s0);
            s1 = MFMA(qf[ch], *(const bf16x8*)&K_lds[16+lr][lg*8+ch*32], s1);
        }
        #pragma unroll
        for (int r=0;r<4;++r){
            float p0 = exp2f(s0[r]*a2r[r] - c2r[r]);   // <= e^4, no max needed
            float p1 = exp2f(s1[r]*a2r[r] - c2r[r]);
            denom[r] += p0 + p1;
            P_lds[wave*16+4*lg+r][lr]    = (bf16)p0;
            P_lds[wave*16+4*lg+r][16+lr] = (bf16)p1;
        }
        __syncthreads();
        // ---- PV: all 128 P-rows x wave's 32 co ----
        bf16x8 vf0 = *(const bf16x8*)(vb + (size_t)lr*NM      + j0 + lg*8);
        bf16x8 vf1 = *(const bf16x8*)(vb + (size_t)(16+lr)*NM + j0 + lg*8);
        #pragma unroll
        for (int rt=0;rt<8;++rt){
            bf16x8 pf = *(const bf16x8*)&P_lds[rt*16+lr][lg*8];
            oacc[rt][0] = MFMA(pf, vf0, oacc[rt][0]);
            oacc[rt][1] = MFMA(pf, vf1, oacc[rt][1]);
        }
    }

    #pragma unroll
    for (int off=1; off<16; off<<=1){
        #pragma unroll
        for (int r=0;r<4;++r) denom[r] += __shfl_xor(denom[r], off);
    }
    if (lr==0){
        #pragma unroll
        for (int r=0;r<4;++r)
            dpart[(size_t)slice*NTOT + row16 + 4*lg + r] = denom[r];
    }
    #pragma unroll
    for (int rt=0;rt<8;++rt){
        #pragma unroll
        for (int ct=0;ct<2;++ct){
            #pragma unroll
            for (int r=0;r<4;++r){
                int row = n0 + rt*16 + 4*lg + r;
                int co  = wave*32 + ct*16 + lr;
                opart[((size_t)slice*NTOT + row)*CD + co] = (bf16)oacc[rt][ct][r];
            }
        }
    }
}

// ---------------- K3b: combine partials -> u = query + O/denom (bf16). GRID 2048 ----------------
__global__ __launch_bounds__(256) void combine_kernel(
    const bf16* __restrict__ opart, const float* __restrict__ dpart,
    const float* __restrict__ query, bf16* __restrict__ u)
{
    int gid = blockIdx.x*256 + threadIdx.x;
    int row = gid>>5, c0 = (gid&31)*8;
    float dsum = dpart[row] + dpart[NTOT+row] + dpart[2*NTOT+row] + dpart[3*(size_t)NTOT+row];
    float inv = 1.0f/dsum;
    float acc[8]={0,0,0,0,0,0,0,0};
    #pragma unroll
    for (int s=0;s<4;++s){
        bf16x8 o = *(const bf16x8*)&opart[((size_t)s*NTOT+row)*CD + c0];
        #pragma unroll
        for (int e=0;e<8;++e) acc[e] += (float)o[e];
    }
    f32x4 qa = *(const f32x4*)(query + (size_t)row*CD + c0);
    f32x4 qb = *(const f32x4*)(query + (size_t)row*CD + c0 + 4);
    bf16x8 out;
    #pragma unroll
    for (int e=0;e<4;++e){
        out[e]   = (bf16)(qa[e] + acc[e]*inv);
        out[4+e] = (bf16)(qb[e] + acc[4+e]*inv);
    }
    *(bf16x8*)&u[(size_t)row*CD + c0] = out;
}

// ---------------- K4: final projection out = u @ Wm^T + bm (fp32 out). GRID 1024 ----------------
__global__ __launch_bounds__(256) void final_kernel(
    const bf16* __restrict__ U, const bf16* __restrict__ W,
    const float* __restrict__ bias, float* __restrict__ out)
{
    const int wave = threadIdx.x>>6, lane = threadIdx.x&63;
    const int lr = lane&15, lg = lane>>4;
    const int n0 = (blockIdx.x>>2)*64 + wave*16;
    const int co0 = (blockIdx.x&3)*64;

    bf16x8 uf[8];
    const bf16* ur = U + (size_t)(n0+lr)*CD + lg*8;
    #pragma unroll
    for (int ch=0; ch<8; ++ch) uf[ch] = *(const bf16x8*)(ur + ch*32);

    f32x4 acc[4];
    #pragma unroll
    for (int t=0;t<4;++t) acc[t]=(f32x4){0,0,0,0};

    #pragma unroll
    for (int t=0;t<4;++t){
        const bf16* wr = W + (size_t)(co0+t*16+lr)*CD + lg*8;
        #pragma unroll
        for (int ch=0; ch<8; ++ch)
            acc[t] = MFMA(*(const bf16x8*)(wr+ch*32), uf[ch], acc[t]);
    }
    const int n = n0 + lr;
    #pragma unroll
    for (int t=0;t<4;++t){
        int co = co0 + t*16 + 4*lg;
        f32x4 o;
        #pragma unroll
        for (int r=0;r<4;++r) o[r] = acc[t][r] + bias[co+r];
        *(f32x4*)(out + (size_t)n*CD + co) = o;
    }
}

extern "C" void kernel_launch(void* const* d_in, const int* in_sizes, int n_in,
                              void* d_out, int out_size, void* d_ws, size_t ws_size,
                              hipStream_t stream)
{
    const float* query = (const float*)d_in[0];
    const float* key_  = (const float*)d_in[1];
    const float* value = (const float*)d_in[2];
    const float* Wq = (const float*)d_in[3];
    const float* bq = (const float*)d_in[4];
    const float* Wk = (const float*)d_in[5];
    const float* bk = (const float*)d_in[6];
    const float* Wv = (const float*)d_in[7];
    const float* bv = (const float*)d_in[8];
    const float* Wm = (const float*)d_in[9];
    const float* bm = (const float*)d_in[10];
    float* out = (float*)d_out;

    bf16* wsb = (bf16*)d_ws;
    bf16* wqb = wsb;                                    // 4 x 65536 bf16 weights
    bf16* wkb = wqb + 65536;
    bf16* wvb = wkb + 65536;
    bf16* wmb = wvb + 65536;
    bf16* qbuf  = wsb + 4*65536;                        // [NTOT][256] bf16
    bf16* kbuf  = qbuf  + (size_t)NTOT*CD;
    bf16* vtbuf = kbuf  + (size_t)NTOT*CD;              // [B][256][NM]
    bf16* ubuf  = vtbuf + (size_t)NTOT*CD;
    float* statsbuf = (float*)(ubuf + (size_t)NTOT*CD); // [NTOT][2] = {c2, a2}
    float* kpart    = statsbuf + (size_t)NTOT*2;        // [4][8][256]
    float* gpart    = kpart + 4*8*256;                  // [4jc][4b][256][256] f32
    bf16*  gbf      = (bf16*)(gpart + (size_t)16*65536);// [4][256][256] bf16
    float* dpart    = (float*)(gbf + (size_t)4*65536);  // [4][NTOT]
    bf16*  opart    = (bf16*)(dpart + (size_t)NTOT*4);  // [4][NTOT][256]

    cvt_w_kernel<<<64,256,0,stream>>>(Wq, Wk, Wv, Wm, wsb);
    proj_kernel<0><<<1024,256,0,stream>>>(query, wqb, bq, qbuf);
    proj_kernel<0><<<1024,256,0,stream>>>(key_,  wkb, bk, kbuf);
    proj_kernel<1><<<1024,256,0,stream>>>(value, wvb, bv, vtbuf);
    ksum_kernel<<<32,256,0,stream>>>(kbuf, kpart);
    gram_kernel<<<64,256,0,stream>>>(kbuf, gpart);
    gfin_kernel<<<1024,256,0,stream>>>(gpart, gbf);
    rowstats_kernel<<<256,256,0,stream>>>(qbuf, gbf, kpart, statsbuf);
    flash_kernel<<<512,512,0,stream>>>(qbuf, kbuf, vtbuf, statsbuf, opart, dpart);
    combine_kernel<<<2048,256,0,stream>>>(opart, dpart, query, ubuf);
    final_kernel<<<1024,256,0,stream>>>(ubuf, wmb, bm, out);
}

// Round 10
// 415.571 us; speedup vs baseline: 1.1981x; 1.1981x over previous
//
#include <hip/hip_runtime.h>
#include <hip/hip_bf16.h>
#include <cmath>

#define CD 256
#define NQ 4096
#define NM 4096
#define NB 4
#define NTOT (NB*NQ)

typedef __bf16 bf16;
typedef __attribute__((ext_vector_type(8))) __bf16 bf16x8;
typedef __attribute__((ext_vector_type(4))) __bf16 bf16x4;
typedef __attribute__((ext_vector_type(4))) float f32x4;

#define MFMA(a,b,c) __builtin_amdgcn_mfma_f32_16x16x32_bf16(a,b,c,0,0,0)

// ---------------- K0: convert the four weight matrices to bf16 ----------------
__global__ __launch_bounds__(256) void cvt_w_kernel(
    const float* __restrict__ wq, const float* __restrict__ wk,
    const float* __restrict__ wv, const float* __restrict__ wm,
    bf16* __restrict__ out)
{
    int i = (blockIdx.x*256 + threadIdx.x)*4;
    const float* srcs[4] = {wq, wk, wv, wm};
    #pragma unroll
    for (int m=0;m<4;++m){
        f32x4 v = *(const f32x4*)(srcs[m]+i);
        bf16x4 o;
        #pragma unroll
        for (int e=0;e<4;++e) o[e] = (bf16)v[e];
        *(bf16x4*)(out + m*65536 + i) = o;
    }
}

// ---------------- K1: projection out = X @ W^T + b (bf16 out). GRID 1024 ----------------
// MODE 0: out[n][co]; MODE 1: out transposed per batch [b][co][m]
template<int MODE>
__global__ __launch_bounds__(256) void proj_kernel(
    const float* __restrict__ X, const bf16* __restrict__ W,
    const float* __restrict__ bias, bf16* __restrict__ out)
{
    const int wave = threadIdx.x>>6, lane = threadIdx.x&63;
    const int lr = lane&15, lg = lane>>4;
    const int n0 = (blockIdx.x>>2)*64 + wave*16;
    const int co0 = (blockIdx.x&3)*64;

    bf16x8 xf[8];
    {
        const float* xr = X + (size_t)(n0+lr)*CD + lg*8;
        #pragma unroll
        for (int ch=0; ch<8; ++ch){
            f32x4 a = *(const f32x4*)(xr + ch*32);
            f32x4 b = *(const f32x4*)(xr + ch*32 + 4);
            bf16x8 t;
            #pragma unroll
            for (int e=0;e<4;++e){ t[e]=(bf16)a[e]; t[4+e]=(bf16)b[e]; }
            xf[ch]=t;
        }
    }
    f32x4 acc[4];
    #pragma unroll
    for (int t=0;t<4;++t) acc[t]=(f32x4){0,0,0,0};

    #pragma unroll
    for (int t=0;t<4;++t){
        const bf16* wr = W + (size_t)(co0+t*16+lr)*CD + lg*8;
        #pragma unroll
        for (int ch=0; ch<8; ++ch){
            bf16x8 wf = *(const bf16x8*)(wr + ch*32);
            if (MODE==0) acc[t] = MFMA(wf, xf[ch], acc[t]);   // D[co, n]
            else         acc[t] = MFMA(xf[ch], wf, acc[t]);   // D[n, co]
        }
    }

    if (MODE==0){
        const int n = n0 + lr;
        #pragma unroll
        for (int t=0;t<4;++t){
            int co = co0 + t*16 + 4*lg;
            bf16x4 o;
            #pragma unroll
            for (int r=0;r<4;++r) o[r] = (bf16)(acc[t][r] + bias[co+r]);
            *(bf16x4*)(out + (size_t)n*CD + co) = o;
        }
    } else {
        const int b = n0 / NM;
        const int m0 = (n0 % NM) + 4*lg;
        #pragma unroll
        for (int t=0;t<4;++t){
            int co = co0 + t*16 + lr;
            float bb = bias[co];
            bf16x4 o;
            #pragma unroll
            for (int r=0;r<4;++r) o[r] = (bf16)(acc[t][r] + bb);
            *(bf16x4*)(out + (size_t)b*CD*NM + (size_t)co*NM + m0) = o;
        }
    }
}

// ---------------- K2a: ksum from K^T rows. GRID 256 (b*64 + c4), 256 thr ----------------
__global__ __launch_bounds__(256) void ksum_kernel(
    const bf16* __restrict__ kt, float* __restrict__ ksum)
{
    const int wave = threadIdx.x>>6, lane = threadIdx.x&63;
    const int b = blockIdx.x>>6, c = (blockIdx.x&63)*4 + wave;
    const bf16* row = kt + (size_t)b*CD*NM + (size_t)c*NM;
    float s = 0.0f;
    #pragma unroll
    for (int i=0;i<8;++i){
        bf16x8 v = *(const bf16x8*)(row + (i*64+lane)*8);
        #pragma unroll
        for (int e=0;e<8;++e) s += (float)v[e];
    }
    #pragma unroll
    for (int off=1; off<64; off<<=1) s += __shfl_xor(s, off);
    if (lane==0) ksum[b*256 + c] = s;
}

// ---------------- K2b: Gram partials G = K^T K from Kt (no transpose). GRID 128 ----------------
// blockIdx = (b*4 + ct)*8 + jc. Wave: G-rows [ct*64+wave*16, +16) x all 256 cols, j-chunk 512.
__global__ __launch_bounds__(256) void gram_kernel(
    const bf16* __restrict__ kt, float* __restrict__ gpart)
{
    const int wave = threadIdx.x>>6, lane = threadIdx.x&63;
    const int lr = lane&15, lg = lane>>4;
    const int b = blockIdx.x>>5, ct = (blockIdx.x>>3)&3, jc = blockIdx.x&7;
    const bf16* ktb = kt + (size_t)b*CD*NM;
    const int c0 = ct*64 + wave*16;

    f32x4 acc[16];
    #pragma unroll
    for (int t=0;t<16;++t) acc[t]=(f32x4){0,0,0,0};

    for (int it=0; it<16; ++it){
        const int j0 = jc*512 + it*32;
        bf16x8 af = *(const bf16x8*)(ktb + (size_t)(c0+lr)*NM + j0 + lg*8);
        #pragma unroll
        for (int t=0;t<16;++t){
            bf16x8 bfr = *(const bf16x8*)(ktb + (size_t)(t*16+lr)*NM + j0 + lg*8);
            acc[t] = MFMA(af, bfr, acc[t]);
        }
    }
    #pragma unroll
    for (int t=0;t<16;++t){
        #pragma unroll
        for (int r=0;r<4;++r){
            int c  = c0 + 4*lg + r;
            int cp = t*16 + lr;
            gpart[(((size_t)jc*4 + b)*256 + c)*256 + cp] = acc[t][r];
        }
    }
}

// ---------------- K2c: reduce 8 Gram partials -> bf16 G. GRID 1024, 256 thr ----------------
__global__ __launch_bounds__(256) void gfin_kernel(
    const float* __restrict__ gpart, bf16* __restrict__ gbf)
{
    int gid = blockIdx.x*256 + threadIdx.x;    // 262144 = 4 b x 65536
    int b = gid>>16, idx = gid&65535;
    float s = 0.0f;
    #pragma unroll
    for (int jc=0;jc<8;++jc) s += gpart[((size_t)jc*4 + b)*65536 + idx];
    gbf[(size_t)b*65536 + idx] = (bf16)s;
}

// ---------------- K2d: per-row stats via Y = Q.G, msq = rowdot(Y,Q). GRID 256 ----------------
// stats[row] = {c2 = mu*a2, a2 = rstd/16*log2e}
__global__ __launch_bounds__(256) void rowstats_kernel(
    const bf16* __restrict__ q, const bf16* __restrict__ gbf,
    const float* __restrict__ ksumg, float* __restrict__ stats)
{
    __shared__ float ksum[256];
    const int wave = threadIdx.x>>6, lane = threadIdx.x&63;
    const int lr = lane&15, lg = lane>>4;
    const int n0 = blockIdx.x*64;
    const int b = n0 / NQ;
    const int row16 = n0 + wave*16;
    ksum[threadIdx.x] = ksumg[b*256 + threadIdx.x];
    __syncthreads();

    bf16x8 qf[8];
    const bf16* qr = q + (size_t)(row16+lr)*CD + lg*8;
    #pragma unroll
    for (int ch=0; ch<8; ++ch) qf[ch] = *(const bf16x8*)(qr + ch*32);

    const bf16* gb = gbf + (size_t)b*65536;
    f32x4 acc[16];
    #pragma unroll
    for (int t=0;t<16;++t) acc[t]=(f32x4){0,0,0,0};
    #pragma unroll
    for (int t=0;t<16;++t){
        #pragma unroll
        for (int ch=0; ch<8; ++ch){
            bf16x8 bf = *(const bf16x8*)&gb[(size_t)(t*16+lr)*256 + ch*32 + lg*8];
            acc[t] = MFMA(qf[ch], bf, acc[t]);   // Y[row][c'] (G symmetric)
        }
    }
    float msq[4]={0,0,0,0}, mean[4]={0,0,0,0};
    #pragma unroll
    for (int t=0;t<16;++t){
        float ks = ksum[t*16+lr];
        #pragma unroll
        for (int r=0;r<4;++r){
            float qv = (float)q[(size_t)(row16+4*lg+r)*CD + t*16+lr];
            msq[r]  = fmaf(acc[t][r], qv, msq[r]);
            mean[r] = fmaf(qv, ks, mean[r]);
        }
    }
    #pragma unroll
    for (int off=1; off<16; off<<=1){
        #pragma unroll
        for (int r=0;r<4;++r){
            msq[r]  += __shfl_xor(msq[r], off);
            mean[r] += __shfl_xor(mean[r], off);
        }
    }
    if (lr==0){
        #pragma unroll
        for (int r=0;r<4;++r){
            int row = row16 + 4*lg + r;
            float mu = mean[r]*(1.0f/NM);
            float ms = msq[r]*(1.0f/NM);
            float var = ms - mu*mu;
            float rstd = rsqrtf(fmaxf(var,0.0f) + 1e-5f);
            float a2 = rstd * (1.0f/16.0f) * 1.4426950408889634f;
            stats[row*2+0] = mu*a2;   // c2
            stats[row*2+1] = a2;
        }
    }
}

// ---------------- K3: flash pass — Q-tile 128, 8 waves, K-LDS prefetch, j-split 4 ----------------
// GRID 512 (qt*4+slice) x 512 threads. No max needed: exponent bounded (z-score <= ~4 nats).
__global__ __launch_bounds__(512) void flash_kernel(
    const bf16* __restrict__ q, const bf16* __restrict__ k,
    const bf16* __restrict__ vt, const float* __restrict__ stats,
    bf16* __restrict__ opart, float* __restrict__ dpart)
{
    __shared__ __align__(16) bf16 K_lds[32][264];
    __shared__ __align__(16) bf16 P_lds[128][40];
    const int wave = threadIdx.x>>6, lane = threadIdx.x&63;
    const int lr = lane&15, lg = lane>>4;
    const int qt = blockIdx.x>>2, slice = blockIdx.x&3;
    const int n0 = qt*128;
    const int b = n0 / NQ;
    const bf16* kb = k  + (size_t)b*NM*CD;
    const bf16* vb = vt + (size_t)b*CD*NM + (size_t)(wave*32)*NM;  // wave's 32-col co-slice
    const int row16 = n0 + wave*16;

    bf16x8 qf[8];
    const bf16* qr = q + (size_t)(row16+lr)*CD + lg*8;
    #pragma unroll
    for (int ch=0; ch<8; ++ch) qf[ch] = *(const bf16x8*)(qr + ch*32);

    float c2r[4], a2r[4];
    #pragma unroll
    for (int r=0;r<4;++r){
        int row = row16 + 4*lg + r;
        c2r[r] = stats[row*2+0];
        a2r[r] = stats[row*2+1];
    }

    f32x4 oacc[8][2];
    #pragma unroll
    for (int rt=0;rt<8;++rt){ oacc[rt][0]=(f32x4){0,0,0,0}; oacc[rt][1]=(f32x4){0,0,0,0}; }
    float denom[4]={0,0,0,0};

    const int jbeg = slice*(NM/4);
    bf16x8 kreg0, kreg1;
    {
        int f0 = threadIdx.x, f1 = threadIdx.x + 512;
        kreg0 = *(const bf16x8*)(kb + (size_t)(jbeg + (f0>>5))*CD + (f0&31)*8);
        kreg1 = *(const bf16x8*)(kb + (size_t)(jbeg + (f1>>5))*CD + (f1&31)*8);
    }
    for (int it=0; it<32; ++it){
        const int j0 = jbeg + it*32;
        {
            int f0 = threadIdx.x, f1 = threadIdx.x + 512;
            *(bf16x8*)&K_lds[f0>>5][(f0&31)*8] = kreg0;
            *(bf16x8*)&K_lds[f1>>5][(f1&31)*8] = kreg1;
        }
        __syncthreads();
        if (it < 31){
            int f0 = threadIdx.x, f1 = threadIdx.x + 512;
            kreg0 = *(const bf16x8*)(kb + (size_t)(j0+32 + (f0>>5))*CD + (f0&31)*8);
            kreg1 = *(const bf16x8*)(kb + (size_t)(j0+32 + (f1>>5))*CD + (f1&31)*8);
        }
        f32x4 s0=(f32x4){0,0,0,0}, s1=(f32x4){0,0,0,0};
        #pragma unroll
        for (int ch=0; ch<8; ++ch){
            s0 = MFMA(qf[ch], *(const bf16x8*)&K_lds[lr][lg*8+ch*32], s0);
            s1 = MFMA(qf[ch], *(const bf16x8*)&K_lds[16+lr][lg*8+ch*32], s1);
        }
        #pragma unroll
        for (int r=0;r<4;++r){
            float p0 = exp2f(s0[r]*a2r[r] - c2r[r]);
            float p1 = exp2f(s1[r]*a2r[r] - c2r[r]);
            denom[r] += p0 + p1;
            P_lds[wave*16+4*lg+r][lr]    = (bf16)p0;
            P_lds[wave*16+4*lg+r][16+lr] = (bf16)p1;
        }
        __syncthreads();
        bf16x8 vf0 = *(const bf16x8*)(vb + (size_t)lr*NM      + j0 + lg*8);
        bf16x8 vf1 = *(const bf16x8*)(vb + (size_t)(16+lr)*NM + j0 + lg*8);
        #pragma unroll
        for (int rt=0;rt<8;++rt){
            bf16x8 pf = *(const bf16x8*)&P_lds[rt*16+lr][lg*8];
            oacc[rt][0] = MFMA(pf, vf0, oacc[rt][0]);
            oacc[rt][1] = MFMA(pf, vf1, oacc[rt][1]);
        }
    }

    #pragma unroll
    for (int off=1; off<16; off<<=1){
        #pragma unroll
        for (int r=0;r<4;++r) denom[r] += __shfl_xor(denom[r], off);
    }
    if (lr==0){
        #pragma unroll
        for (int r=0;r<4;++r)
            dpart[(size_t)slice*NTOT + row16 + 4*lg + r] = denom[r];
    }
    #pragma unroll
    for (int rt=0;rt<8;++rt){
        #pragma unroll
        for (int ct=0;ct<2;++ct){
            #pragma unroll
            for (int r=0;r<4;++r){
                int row = n0 + rt*16 + 4*lg + r;
                int co  = wave*32 + ct*16 + lr;
                opart[((size_t)slice*NTOT + row)*CD + co] = (bf16)oacc[rt][ct][r];
            }
        }
    }
}

// ---------------- K3b: combine partials -> u = query + O/denom (bf16). GRID 2048 ----------------
__global__ __launch_bounds__(256) void combine_kernel(
    const bf16* __restrict__ opart, const float* __restrict__ dpart,
    const float* __restrict__ query, bf16* __restrict__ u)
{
    int gid = blockIdx.x*256 + threadIdx.x;
    int row = gid>>5, c0 = (gid&31)*8;
    float dsum = dpart[row] + dpart[NTOT+row] + dpart[2*NTOT+row] + dpart[3*(size_t)NTOT+row];
    float inv = 1.0f/dsum;
    float acc[8]={0,0,0,0,0,0,0,0};
    #pragma unroll
    for (int s=0;s<4;++s){
        bf16x8 o = *(const bf16x8*)&opart[((size_t)s*NTOT+row)*CD + c0];
        #pragma unroll
        for (int e=0;e<8;++e) acc[e] += (float)o[e];
    }
    f32x4 qa = *(const f32x4*)(query + (size_t)row*CD + c0);
    f32x4 qb = *(const f32x4*)(query + (size_t)row*CD + c0 + 4);
    bf16x8 out;
    #pragma unroll
    for (int e=0;e<4;++e){
        out[e]   = (bf16)(qa[e] + acc[e]*inv);
        out[4+e] = (bf16)(qb[e] + acc[4+e]*inv);
    }
    *(bf16x8*)&u[(size_t)row*CD + c0] = out;
}

// ---------------- K4: final projection out = u @ Wm^T + bm (fp32 out). GRID 1024 ----------------
__global__ __launch_bounds__(256) void final_kernel(
    const bf16* __restrict__ U, const bf16* __restrict__ W,
    const float* __restrict__ bias, float* __restrict__ out)
{
    const int wave = threadIdx.x>>6, lane = threadIdx.x&63;
    const int lr = lane&15, lg = lane>>4;
    const int n0 = (blockIdx.x>>2)*64 + wave*16;
    const int co0 = (blockIdx.x&3)*64;

    bf16x8 uf[8];
    const bf16* ur = U + (size_t)(n0+lr)*CD + lg*8;
    #pragma unroll
    for (int ch=0; ch<8; ++ch) uf[ch] = *(const bf16x8*)(ur + ch*32);

    f32x4 acc[4];
    #pragma unroll
    for (int t=0;t<4;++t) acc[t]=(f32x4){0,0,0,0};

    #pragma unroll
    for (int t=0;t<4;++t){
        const bf16* wr = W + (size_t)(co0+t*16+lr)*CD + lg*8;
        #pragma unroll
        for (int ch=0; ch<8; ++ch)
            acc[t] = MFMA(*(const bf16x8*)(wr+ch*32), uf[ch], acc[t]);
    }
    const int n = n0 + lr;
    #pragma unroll
    for (int t=0;t<4;++t){
        int co = co0 + t*16 + 4*lg;
        f32x4 o;
        #pragma unroll
        for (int r=0;r<4;++r) o[r] = acc[t][r] + bias[co+r];
        *(f32x4*)(out + (size_t)n*CD + co) = o;
    }
}

extern "C" void kernel_launch(void* const* d_in, const int* in_sizes, int n_in,
                              void* d_out, int out_size, void* d_ws, size_t ws_size,
                              hipStream_t stream)
{
    const float* query = (const float*)d_in[0];
    const float* key_  = (const float*)d_in[1];
    const float* value = (const float*)d_in[2];
    const float* Wq = (const float*)d_in[3];
    const float* bq = (const float*)d_in[4];
    const float* Wk = (const float*)d_in[5];
    const float* bk = (const float*)d_in[6];
    const float* Wv = (const float*)d_in[7];
    const float* bv = (const float*)d_in[8];
    const float* Wm = (const float*)d_in[9];
    const float* bm = (const float*)d_in[10];
    float* out = (float*)d_out;

    bf16* wsb = (bf16*)d_ws;
    bf16* wqb = wsb;                                    // 4 x 65536 bf16 weights
    bf16* wkb = wqb + 65536;
    bf16* wvb = wkb + 65536;
    bf16* wmb = wvb + 65536;
    bf16* qbuf  = wsb + 4*65536;                        // [NTOT][256] bf16
    bf16* kbuf  = qbuf  + (size_t)NTOT*CD;              // [NTOT][256] bf16
    bf16* vtbuf = kbuf  + (size_t)NTOT*CD;              // [B][256][NM] bf16
    float* statsbuf = (float*)(vtbuf + (size_t)NTOT*CD);// [NTOT][2] = {c2, a2}
    float* ksumbuf  = statsbuf + (size_t)NTOT*2;        // [4][256]
    bf16*  gbf      = (bf16*)(ksumbuf + 1024);          // [4][256][256] bf16
    float* dpart    = (float*)(gbf + (size_t)4*65536);  // [4][NTOT]
    bf16*  opart    = (bf16*)(dpart + (size_t)NTOT*4);  // [4][NTOT][256] bf16 (32 MB)
    bf16*  ktbuf    = opart;                            // ALIAS: Kt [B][256][NM], dead before flash
    float* gpart    = (float*)(opart + (size_t)4*NTOT*CD); // [8][4][256][256] f32 (8 MB)
    bf16*  ubuf     = (bf16*)gpart;                     // ALIAS: u, live after gpart dead

    cvt_w_kernel<<<64,256,0,stream>>>(Wq, Wk, Wv, Wm, wsb);
    proj_kernel<0><<<1024,256,0,stream>>>(query, wqb, bq, qbuf);
    proj_kernel<0><<<1024,256,0,stream>>>(key_,  wkb, bk, kbuf);
    proj_kernel<1><<<1024,256,0,stream>>>(key_,  wkb, bk, ktbuf);   // K^T for Gram/ksum
    proj_kernel<1><<<1024,256,0,stream>>>(value, wvb, bv, vtbuf);
    ksum_kernel<<<256,256,0,stream>>>(ktbuf, ksumbuf);
    gram_kernel<<<128,256,0,stream>>>(ktbuf, gpart);
    gfin_kernel<<<1024,256,0,stream>>>(gpart, gbf);
    rowstats_kernel<<<256,256,0,stream>>>(qbuf, gbf, ksumbuf, statsbuf);
    flash_kernel<<<512,512,0,stream>>>(qbuf, kbuf, vtbuf, statsbuf, opart, dpart); // clobbers ktbuf (dead)
    combine_kernel<<<2048,256,0,stream>>>(opart, dpart, query, ubuf);              // ubuf over gpart (dead)
    final_kernel<<<1024,256,0,stream>>>(ubuf, wmb, bm, out);
}

// Round 12
// 407.066 us; speedup vs baseline: 1.2231x; 1.0209x over previous
//
#include <hip/hip_runtime.h>
#include <hip/hip_bf16.h>
#include <cmath>

#define CD 256
#define NQ 4096
#define NM 4096
#define NB 4
#define NTOT (NB*NQ)

typedef __bf16 bf16;
typedef __attribute__((ext_vector_type(8))) __bf16 bf16x8;
typedef __attribute__((ext_vector_type(4))) __bf16 bf16x4;
typedef __attribute__((ext_vector_type(4))) float f32x4;

#define MFMA(a,b,c) __builtin_amdgcn_mfma_f32_16x16x32_bf16(a,b,c,0,0,0)

// ---------------- K0: convert the four weight matrices to bf16 ----------------
__global__ __launch_bounds__(256) void cvt_w_kernel(
    const float* __restrict__ wq, const float* __restrict__ wk,
    const float* __restrict__ wv, const float* __restrict__ wm,
    bf16* __restrict__ out)
{
    int i = (blockIdx.x*256 + threadIdx.x)*4;
    const float* srcs[4] = {wq, wk, wv, wm};
    #pragma unroll
    for (int m=0;m<4;++m){
        f32x4 v = *(const f32x4*)(srcs[m]+i);
        bf16x4 o;
        #pragma unroll
        for (int e=0;e<4;++e) o[e] = (bf16)v[e];
        *(bf16x4*)(out + m*65536 + i) = o;
    }
}

// ---------------- K1: projection out = X @ W^T + b (bf16). GRID 1024 ----------------
// MODE 0: out[n][co] row-major.  MODE 1: out2[b][co][m] transposed.
// MODE 2: BOTH (key): row-major -> out, transposed -> out2 (one X read).
template<int MODE>
__global__ __launch_bounds__(256) void proj_kernel(
    const float* __restrict__ X, const bf16* __restrict__ W,
    const float* __restrict__ bias, bf16* __restrict__ out, bf16* __restrict__ out2)
{
    const int wave = threadIdx.x>>6, lane = threadIdx.x&63;
    const int lr = lane&15, lg = lane>>4;
    const int n0 = (blockIdx.x>>2)*64 + wave*16;
    const int co0 = (blockIdx.x&3)*64;

    bf16x8 xf[8];
    {
        const float* xr = X + (size_t)(n0+lr)*CD + lg*8;
        #pragma unroll
        for (int ch=0; ch<8; ++ch){
            f32x4 a = *(const f32x4*)(xr + ch*32);
            f32x4 b = *(const f32x4*)(xr + ch*32 + 4);
            bf16x8 t;
            #pragma unroll
            for (int e=0;e<4;++e){ t[e]=(bf16)a[e]; t[4+e]=(bf16)b[e]; }
            xf[ch]=t;
        }
    }
    f32x4 acc[4], acc2[4];
    #pragma unroll
    for (int t=0;t<4;++t){ acc[t]=(f32x4){0,0,0,0}; acc2[t]=(f32x4){0,0,0,0}; }

    #pragma unroll
    for (int t=0;t<4;++t){
        const bf16* wr = W + (size_t)(co0+t*16+lr)*CD + lg*8;
        #pragma unroll
        for (int ch=0; ch<8; ++ch){
            bf16x8 wf = *(const bf16x8*)(wr + ch*32);
            if (MODE==0)      acc[t]  = MFMA(wf, xf[ch], acc[t]);    // D[co, n]
            else if (MODE==1) acc2[t] = MFMA(xf[ch], wf, acc2[t]);   // D[n, co]
            else {            acc[t]  = MFMA(wf, xf[ch], acc[t]);
                              acc2[t] = MFMA(xf[ch], wf, acc2[t]); }
        }
    }

    if (MODE==0 || MODE==2){
        const int n = n0 + lr;
        #pragma unroll
        for (int t=0;t<4;++t){
            int co = co0 + t*16 + 4*lg;
            bf16x4 o;
            #pragma unroll
            for (int r=0;r<4;++r) o[r] = (bf16)(acc[t][r] + bias[co+r]);
            *(bf16x4*)(out + (size_t)n*CD + co) = o;
        }
    }
    if (MODE==1 || MODE==2){
        const int b = n0 / NM;
        const int m0 = (n0 % NM) + 4*lg;
        #pragma unroll
        for (int t=0;t<4;++t){
            int co = co0 + t*16 + lr;
            float bb = bias[co];
            bf16x4 o;
            #pragma unroll
            for (int r=0;r<4;++r) o[r] = (bf16)(acc2[t][r] + bb);
            *(bf16x4*)(out2 + (size_t)b*CD*NM + (size_t)co*NM + m0) = o;
        }
    }
}

// ---------------- K2a: ksum from K^T rows. GRID 256, 256 thr ----------------
__global__ __launch_bounds__(256) void ksum_kernel(
    const bf16* __restrict__ kt, float* __restrict__ ksum)
{
    const int wave = threadIdx.x>>6, lane = threadIdx.x&63;
    const int b = blockIdx.x>>6, c = (blockIdx.x&63)*4 + wave;
    const bf16* row = kt + (size_t)b*CD*NM + (size_t)c*NM;
    float s = 0.0f;
    #pragma unroll
    for (int i=0;i<8;++i){
        bf16x8 v = *(const bf16x8*)(row + (i*64+lane)*8);
        #pragma unroll
        for (int e=0;e<8;++e) s += (float)v[e];
    }
    #pragma unroll
    for (int off=1; off<64; off<<=1) s += __shfl_xor(s, off);
    if (lane==0) ksum[b*256 + c] = s;
}

// ---------------- K2b: Gram partials G = K^T K from Kt. GRID 128 ----------------
__global__ __launch_bounds__(256) void gram_kernel(
    const bf16* __restrict__ kt, float* __restrict__ gpart)
{
    const int wave = threadIdx.x>>6, lane = threadIdx.x&63;
    const int lr = lane&15, lg = lane>>4;
    const int b = blockIdx.x>>5, ct = (blockIdx.x>>3)&3, jc = blockIdx.x&7;
    const bf16* ktb = kt + (size_t)b*CD*NM;
    const int c0 = ct*64 + wave*16;

    f32x4 acc[16];
    #pragma unroll
    for (int t=0;t<16;++t) acc[t]=(f32x4){0,0,0,0};

    for (int it=0; it<16; ++it){
        const int j0 = jc*512 + it*32;
        bf16x8 af = *(const bf16x8*)(ktb + (size_t)(c0+lr)*NM + j0 + lg*8);
        #pragma unroll
        for (int t=0;t<16;++t){
            bf16x8 bfr = *(const bf16x8*)(ktb + (size_t)(t*16+lr)*NM + j0 + lg*8);
            acc[t] = MFMA(af, bfr, acc[t]);
        }
    }
    #pragma unroll
    for (int t=0;t<16;++t){
        #pragma unroll
        for (int r=0;r<4;++r){
            int c  = c0 + 4*lg + r;
            int cp = t*16 + lr;
            gpart[(((size_t)jc*4 + b)*256 + c)*256 + cp] = acc[t][r];
        }
    }
}

// ---------------- K2c: reduce 8 Gram partials -> bf16 G. GRID 1024 ----------------
__global__ __launch_bounds__(256) void gfin_kernel(
    const float* __restrict__ gpart, bf16* __restrict__ gbf)
{
    int gid = blockIdx.x*256 + threadIdx.x;
    int b = gid>>16, idx = gid&65535;
    float s = 0.0f;
    #pragma unroll
    for (int jc=0;jc<8;++jc) s += gpart[((size_t)jc*4 + b)*65536 + idx];
    gbf[(size_t)b*65536 + idx] = (bf16)s;
}

// ---------------- K2d: per-row stats via Y = Q.G. GRID 256 ----------------
__global__ __launch_bounds__(256) void rowstats_kernel(
    const bf16* __restrict__ q, const bf16* __restrict__ gbf,
    const float* __restrict__ ksumg, float* __restrict__ stats)
{
    __shared__ float ksum[256];
    const int wave = threadIdx.x>>6, lane = threadIdx.x&63;
    const int lr = lane&15, lg = lane>>4;
    const int n0 = blockIdx.x*64;
    const int b = n0 / NQ;
    const int row16 = n0 + wave*16;
    ksum[threadIdx.x] = ksumg[b*256 + threadIdx.x];
    __syncthreads();

    bf16x8 qf[8];
    const bf16* qr = q + (size_t)(row16+lr)*CD + lg*8;
    #pragma unroll
    for (int ch=0; ch<8; ++ch) qf[ch] = *(const bf16x8*)(qr + ch*32);

    const bf16* gb = gbf + (size_t)b*65536;
    f32x4 acc[16];
    #pragma unroll
    for (int t=0;t<16;++t) acc[t]=(f32x4){0,0,0,0};
    #pragma unroll
    for (int t=0;t<16;++t){
        #pragma unroll
        for (int ch=0; ch<8; ++ch){
            bf16x8 bf = *(const bf16x8*)&gb[(size_t)(t*16+lr)*256 + ch*32 + lg*8];
            acc[t] = MFMA(qf[ch], bf, acc[t]);
        }
    }
    float msq[4]={0,0,0,0}, mean[4]={0,0,0,0};
    #pragma unroll
    for (int t=0;t<16;++t){
        float ks = ksum[t*16+lr];
        #pragma unroll
        for (int r=0;r<4;++r){
            float qv = (float)q[(size_t)(row16+4*lg+r)*CD + t*16+lr];
            msq[r]  = fmaf(acc[t][r], qv, msq[r]);
            mean[r] = fmaf(qv, ks, mean[r]);
        }
    }
    #pragma unroll
    for (int off=1; off<16; off<<=1){
        #pragma unroll
        for (int r=0;r<4;++r){
            msq[r]  += __shfl_xor(msq[r], off);
            mean[r] += __shfl_xor(mean[r], off);
        }
    }
    if (lr==0){
        #pragma unroll
        for (int r=0;r<4;++r){
            int row = row16 + 4*lg + r;
            float mu = mean[r]*(1.0f/NM);
            float ms = msq[r]*(1.0f/NM);
            float var = ms - mu*mu;
            float rstd = rsqrtf(fmaxf(var,0.0f) + 1e-5f);
            float a2 = rstd * (1.0f/16.0f) * 1.4426950408889634f;
            stats[row*2+0] = mu*a2;   // c2
            stats[row*2+1] = a2;
        }
    }
}

// ---------------- K3: flash — Q-tile 128, j-tile 64 (half the barriers), j-split 4 ----------------
// GRID 512 (qt*4+slice) x 512 threads.
__global__ __launch_bounds__(512) void flash_kernel(
    const bf16* __restrict__ q, const bf16* __restrict__ k,
    const bf16* __restrict__ vt, const float* __restrict__ stats,
    bf16* __restrict__ opart, float* __restrict__ dpart)
{
    __shared__ __align__(16) bf16 K_lds[64][264];   // 33.8 KB
    __shared__ __align__(16) bf16 P_lds[128][72];   // 18.4 KB
    const int wave = threadIdx.x>>6, lane = threadIdx.x&63;
    const int lr = lane&15, lg = lane>>4;
    const int qt = blockIdx.x>>2, slice = blockIdx.x&3;
    const int n0 = qt*128;
    const int b = n0 / NQ;
    const bf16* kb = k  + (size_t)b*NM*CD;
    const bf16* vb = vt + (size_t)b*CD*NM + (size_t)(wave*32)*NM;
    const int row16 = n0 + wave*16;

    bf16x8 qf[8];
    const bf16* qr = q + (size_t)(row16+lr)*CD + lg*8;
    #pragma unroll
    for (int ch=0; ch<8; ++ch) qf[ch] = *(const bf16x8*)(qr + ch*32);

    float c2r[4], a2r[4];
    #pragma unroll
    for (int r=0;r<4;++r){
        int row = row16 + 4*lg + r;
        c2r[r] = stats[row*2+0];
        a2r[r] = stats[row*2+1];
    }

    f32x4 oacc[8][2];
    #pragma unroll
    for (int rt=0;rt<8;++rt){ oacc[rt][0]=(f32x4){0,0,0,0}; oacc[rt][1]=(f32x4){0,0,0,0}; }
    float denom[4]={0,0,0,0};

    const int jbeg = slice*(NM/4);
    bf16x8 kreg[4];
    #pragma unroll
    for (int p=0;p<4;++p){
        int f = threadIdx.x + p*512;
        kreg[p] = *(const bf16x8*)(kb + (size_t)(jbeg + (f>>5))*CD + (f&31)*8);
    }
    for (int it=0; it<16; ++it){
        const int j0 = jbeg + it*64;
        #pragma unroll
        for (int p=0;p<4;++p){
            int f = threadIdx.x + p*512;
            *(bf16x8*)&K_lds[f>>5][(f&31)*8] = kreg[p];
        }
        __syncthreads();
        if (it < 15){
            #pragma unroll
            for (int p=0;p<4;++p){
                int f = threadIdx.x + p*512;
                kreg[p] = *(const bf16x8*)(kb + (size_t)(j0+64 + (f>>5))*CD + (f&31)*8);
            }
        }
        // ---- QK: wave's 16 rows x 64 j (4 independent 16-j chains) ----
        f32x4 s0=(f32x4){0,0,0,0}, s1=(f32x4){0,0,0,0};
        f32x4 s2=(f32x4){0,0,0,0}, s3=(f32x4){0,0,0,0};
        #pragma unroll
        for (int ch=0; ch<8; ++ch){
            s0 = MFMA(qf[ch], *(const bf16x8*)&K_lds[     lr][lg*8+ch*32], s0);
            s1 = MFMA(qf[ch], *(const bf16x8*)&K_lds[16+lr][lg*8+ch*32], s1);
            s2 = MFMA(qf[ch], *(const bf16x8*)&K_lds[32+lr][lg*8+ch*32], s2);
            s3 = MFMA(qf[ch], *(const bf16x8*)&K_lds[48+lr][lg*8+ch*32], s3);
        }
        #pragma unroll
        for (int r=0;r<4;++r){
            float p0 = exp2f(s0[r]*a2r[r] - c2r[r]);
            float p1 = exp2f(s1[r]*a2r[r] - c2r[r]);
            float p2 = exp2f(s2[r]*a2r[r] - c2r[r]);
            float p3 = exp2f(s3[r]*a2r[r] - c2r[r]);
            denom[r] += (p0 + p1) + (p2 + p3);
            int prow = wave*16 + 4*lg + r;
            P_lds[prow][lr]    = (bf16)p0;
            P_lds[prow][16+lr] = (bf16)p1;
            P_lds[prow][32+lr] = (bf16)p2;
            P_lds[prow][48+lr] = (bf16)p3;
        }
        __syncthreads();
        // ---- PV: all 128 P-rows x wave's 32 co, k=64 ----
        #pragma unroll
        for (int w=0; w<2; ++w){
            bf16x8 vf0 = *(const bf16x8*)(vb + (size_t)lr*NM      + j0 + w*32 + lg*8);
            bf16x8 vf1 = *(const bf16x8*)(vb + (size_t)(16+lr)*NM + j0 + w*32 + lg*8);
            #pragma unroll
            for (int rt=0;rt<8;++rt){
                bf16x8 pf = *(const bf16x8*)&P_lds[rt*16+lr][w*32+lg*8];
                oacc[rt][0] = MFMA(pf, vf0, oacc[rt][0]);
                oacc[rt][1] = MFMA(pf, vf1, oacc[rt][1]);
            }
        }
    }

    #pragma unroll
    for (int off=1; off<16; off<<=1){
        #pragma unroll
        for (int r=0;r<4;++r) denom[r] += __shfl_xor(denom[r], off);
    }
    if (lr==0){
        #pragma unroll
        for (int r=0;r<4;++r)
            dpart[(size_t)slice*NTOT + row16 + 4*lg + r] = denom[r];
    }
    #pragma unroll
    for (int rt=0;rt<8;++rt){
        #pragma unroll
        for (int ct=0;ct<2;++ct){
            #pragma unroll
            for (int r=0;r<4;++r){
                int row = n0 + rt*16 + 4*lg + r;
                int co  = wave*32 + ct*16 + lr;
                opart[((size_t)slice*NTOT + row)*CD + co] = (bf16)oacc[rt][ct][r];
            }
        }
    }
}

// ---------------- K3b: dinv[row] = 1/sum_s dpart[s][row]. GRID 64 ----------------
__global__ __launch_bounds__(256) void dinv_kernel(
    const float* __restrict__ dpart, float* __restrict__ dinv)
{
    int row = blockIdx.x*256 + threadIdx.x;
    dinv[row] = 1.0f / (dpart[row] + dpart[NTOT+row]
                      + dpart[2*(size_t)NTOT+row] + dpart[3*(size_t)NTOT+row]);
}

// ---------------- K4: fused combine + final projection. GRID 1024 ----------------
// u = query + (sum_s opart)/denom built in-register, then out = u @ Wm^T + bm (fp32).
__global__ __launch_bounds__(256) void final_kernel(
    const bf16* __restrict__ opart, const float* __restrict__ dinv,
    const float* __restrict__ query, const bf16* __restrict__ W,
    const float* __restrict__ bias, float* __restrict__ out)
{
    const int wave = threadIdx.x>>6, lane = threadIdx.x&63;
    const int lr = lane&15, lg = lane>>4;
    const int n0 = (blockIdx.x>>2)*64 + wave*16;
    const int co0 = (blockIdx.x&3)*64;
    const int n = n0 + lr;
    const float di = dinv[n];

    bf16x8 uf[8];
    #pragma unroll
    for (int ch=0; ch<8; ++ch){
        const int c = lg*8 + ch*32;
        float a[8];
        f32x4 qa = *(const f32x4*)(query + (size_t)n*CD + c);
        f32x4 qb = *(const f32x4*)(query + (size_t)n*CD + c + 4);
        #pragma unroll
        for (int e=0;e<4;++e){ a[e]=qa[e]; a[4+e]=qb[e]; }
        #pragma unroll
        for (int s=0;s<4;++s){
            bf16x8 o = *(const bf16x8*)&opart[((size_t)s*NTOT + n)*CD + c];
            #pragma unroll
            for (int e=0;e<8;++e) a[e] = fmaf((float)o[e], di, a[e]);
        }
        bf16x8 t;
        #pragma unroll
        for (int e=0;e<8;++e) t[e] = (bf16)a[e];
        uf[ch] = t;
    }

    f32x4 acc[4];
    #pragma unroll
    for (int t=0;t<4;++t) acc[t]=(f32x4){0,0,0,0};
    #pragma unroll
    for (int t=0;t<4;++t){
        const bf16* wr = W + (size_t)(co0+t*16+lr)*CD + lg*8;
        #pragma unroll
        for (int ch=0; ch<8; ++ch)
            acc[t] = MFMA(*(const bf16x8*)(wr+ch*32), uf[ch], acc[t]);
    }
    #pragma unroll
    for (int t=0;t<4;++t){
        int co = co0 + t*16 + 4*lg;
        f32x4 o;
        #pragma unroll
        for (int r=0;r<4;++r) o[r] = acc[t][r] + bias[co+r];
        *(f32x4*)(out + (size_t)n*CD + co) = o;
    }
}

extern "C" void kernel_launch(void* const* d_in, const int* in_sizes, int n_in,
                              void* d_out, int out_size, void* d_ws, size_t ws_size,
                              hipStream_t stream)
{
    const float* query = (const float*)d_in[0];
    const float* key_  = (const float*)d_in[1];
    const float* value = (const float*)d_in[2];
    const float* Wq = (const float*)d_in[3];
    const float* bq = (const float*)d_in[4];
    const float* Wk = (const float*)d_in[5];
    const float* bk = (const float*)d_in[6];
    const float* Wv = (const float*)d_in[7];
    const float* bv = (const float*)d_in[8];
    const float* Wm = (const float*)d_in[9];
    const float* bm = (const float*)d_in[10];
    float* out = (float*)d_out;

    bf16* wsb = (bf16*)d_ws;
    bf16* wqb = wsb;                                    // 4 x 65536 bf16 weights
    bf16* wkb = wqb + 65536;
    bf16* wvb = wkb + 65536;
    bf16* wmb = wvb + 65536;
    bf16* qbuf  = wsb + 4*65536;                        // [NTOT][256] bf16
    bf16* kbuf  = qbuf  + (size_t)NTOT*CD;              // [NTOT][256] bf16
    bf16* vtbuf = kbuf  + (size_t)NTOT*CD;              // [B][256][NM] bf16
    float* statsbuf = (float*)(vtbuf + (size_t)NTOT*CD);// [NTOT][2] = {c2, a2}
    float* ksumbuf  = statsbuf + (size_t)NTOT*2;        // [4][256]
    float* dinvbuf  = ksumbuf + 1024;                   // [NTOT]
    bf16*  gbf      = (bf16*)(dinvbuf + NTOT);          // [4][256][256] bf16
    float* dpart    = (float*)(gbf + (size_t)4*65536);  // [4][NTOT]
    bf16*  opart    = (bf16*)(dpart + (size_t)NTOT*4);  // [4][NTOT][256] bf16 (32 MB)
    bf16*  ktbuf    = opart;                            // ALIAS: Kt [B][256][NM], dead before flash
    float* gpart    = (float*)(opart + (size_t)4*NTOT*CD); // [8][4][256][256] f32 (8 MB)

    cvt_w_kernel<<<64,256,0,stream>>>(Wq, Wk, Wv, Wm, wsb);
    proj_kernel<0><<<1024,256,0,stream>>>(query, wqb, bq, qbuf,  nullptr);
    proj_kernel<2><<<1024,256,0,stream>>>(key_,  wkb, bk, kbuf,  ktbuf);   // kbuf + Kt in one pass
    proj_kernel<1><<<1024,256,0,stream>>>(value, wvb, bv, nullptr, vtbuf);
    ksum_kernel<<<256,256,0,stream>>>(ktbuf, ksumbuf);
    gram_kernel<<<128,256,0,stream>>>(ktbuf, gpart);
    gfin_kernel<<<1024,256,0,stream>>>(gpart, gbf);
    rowstats_kernel<<<256,256,0,stream>>>(qbuf, gbf, ksumbuf, statsbuf);
    flash_kernel<<<512,512,0,stream>>>(qbuf, kbuf, vtbuf, statsbuf, opart, dpart); // clobbers ktbuf (dead)
    dinv_kernel<<<64,256,0,stream>>>(dpart, dinvbuf);
    final_kernel<<<1024,256,0,stream>>>(opart, dinvbuf, query, wmb, bm, out);
}

// Round 13
// 398.224 us; speedup vs baseline: 1.2503x; 1.0222x over previous
//
#include <hip/hip_runtime.h>
#include <hip/hip_bf16.h>
#include <cmath>

#define CD 256
#define NQ 4096
#define NM 4096
#define NB 4
#define NTOT (NB*NQ)

typedef __bf16 bf16;
typedef __attribute__((ext_vector_type(8))) __bf16 bf16x8;
typedef __attribute__((ext_vector_type(4))) __bf16 bf16x4;
typedef __attribute__((ext_vector_type(4))) float f32x4;

#define MFMA(a,b,c) __builtin_amdgcn_mfma_f32_16x16x32_bf16(a,b,c,0,0,0)

// ---------------- K0: convert the four weight matrices to bf16 ----------------
__global__ __launch_bounds__(256) void cvt_w_kernel(
    const float* __restrict__ wq, const float* __restrict__ wk,
    const float* __restrict__ wv, const float* __restrict__ wm,
    bf16* __restrict__ out)
{
    int i = (blockIdx.x*256 + threadIdx.x)*4;
    const float* srcs[4] = {wq, wk, wv, wm};
    #pragma unroll
    for (int m=0;m<4;++m){
        f32x4 v = *(const f32x4*)(srcs[m]+i);
        bf16x4 o;
        #pragma unroll
        for (int e=0;e<4;++e) o[e] = (bf16)v[e];
        *(bf16x4*)(out + m*65536 + i) = o;
    }
}

// ---------------- K1: projection out = X @ W^T + b (bf16). GRID 1024 ----------------
// XCD-friendly split: rowblk = bid & 255 (low bits), co = bid >> 8 (high bits)
// so the 4 blocks sharing an X row-tile are 256 apart -> same XCD L2.
// MODE 0: out[n][co].  MODE 1: out2[b][co][m].  MODE 2: both (key).
template<int MODE>
__global__ __launch_bounds__(256) void proj_kernel(
    const float* __restrict__ X, const bf16* __restrict__ W,
    const float* __restrict__ bias, bf16* __restrict__ out, bf16* __restrict__ out2)
{
    const int wave = threadIdx.x>>6, lane = threadIdx.x&63;
    const int lr = lane&15, lg = lane>>4;
    const int n0 = (blockIdx.x & 255)*64 + wave*16;
    const int co0 = (blockIdx.x >> 8)*64;

    bf16x8 xf[8];
    {
        const float* xr = X + (size_t)(n0+lr)*CD + lg*8;
        #pragma unroll
        for (int ch=0; ch<8; ++ch){
            f32x4 a = *(const f32x4*)(xr + ch*32);
            f32x4 b = *(const f32x4*)(xr + ch*32 + 4);
            bf16x8 t;
            #pragma unroll
            for (int e=0;e<4;++e){ t[e]=(bf16)a[e]; t[4+e]=(bf16)b[e]; }
            xf[ch]=t;
        }
    }
    f32x4 acc[4], acc2[4];
    #pragma unroll
    for (int t=0;t<4;++t){ acc[t]=(f32x4){0,0,0,0}; acc2[t]=(f32x4){0,0,0,0}; }

    #pragma unroll
    for (int t=0;t<4;++t){
        const bf16* wr = W + (size_t)(co0+t*16+lr)*CD + lg*8;
        #pragma unroll
        for (int ch=0; ch<8; ++ch){
            bf16x8 wf = *(const bf16x8*)(wr + ch*32);
            if (MODE==0)      acc[t]  = MFMA(wf, xf[ch], acc[t]);    // D[co, n]
            else if (MODE==1) acc2[t] = MFMA(xf[ch], wf, acc2[t]);   // D[n, co]
            else {            acc[t]  = MFMA(wf, xf[ch], acc[t]);
                              acc2[t] = MFMA(xf[ch], wf, acc2[t]); }
        }
    }

    if (MODE==0 || MODE==2){
        const int n = n0 + lr;
        #pragma unroll
        for (int t=0;t<4;++t){
            int co = co0 + t*16 + 4*lg;
            bf16x4 o;
            #pragma unroll
            for (int r=0;r<4;++r) o[r] = (bf16)(acc[t][r] + bias[co+r]);
            *(bf16x4*)(out + (size_t)n*CD + co) = o;
        }
    }
    if (MODE==1 || MODE==2){
        const int b = n0 / NM;
        const int m0 = (n0 % NM) + 4*lg;
        #pragma unroll
        for (int t=0;t<4;++t){
            int co = co0 + t*16 + lr;
            float bb = bias[co];
            bf16x4 o;
            #pragma unroll
            for (int r=0;r<4;++r) o[r] = (bf16)(acc2[t][r] + bb);
            *(bf16x4*)(out2 + (size_t)b*CD*NM + (size_t)co*NM + m0) = o;
        }
    }
}

// ---------------- K2a: ksum from K^T rows. GRID 256, 256 thr ----------------
__global__ __launch_bounds__(256) void ksum_kernel(
    const bf16* __restrict__ kt, float* __restrict__ ksum)
{
    const int wave = threadIdx.x>>6, lane = threadIdx.x&63;
    const int b = blockIdx.x>>6, c = (blockIdx.x&63)*4 + wave;
    const bf16* row = kt + (size_t)b*CD*NM + (size_t)c*NM;
    float s = 0.0f;
    #pragma unroll
    for (int i=0;i<8;++i){
        bf16x8 v = *(const bf16x8*)(row + (i*64+lane)*8);
        #pragma unroll
        for (int e=0;e<8;++e) s += (float)v[e];
    }
    #pragma unroll
    for (int off=1; off<64; off<<=1) s += __shfl_xor(s, off);
    if (lane==0) ksum[b*256 + c] = s;
}

// ---------------- K2b: Gram partials G = K^T K from Kt. GRID 128 ----------------
__global__ __launch_bounds__(256) void gram_kernel(
    const bf16* __restrict__ kt, float* __restrict__ gpart)
{
    const int wave = threadIdx.x>>6, lane = threadIdx.x&63;
    const int lr = lane&15, lg = lane>>4;
    const int b = blockIdx.x>>5, ct = (blockIdx.x>>3)&3, jc = blockIdx.x&7;
    const bf16* ktb = kt + (size_t)b*CD*NM;
    const int c0 = ct*64 + wave*16;

    f32x4 acc[16];
    #pragma unroll
    for (int t=0;t<16;++t) acc[t]=(f32x4){0,0,0,0};

    for (int it=0; it<16; ++it){
        const int j0 = jc*512 + it*32;
        bf16x8 af = *(const bf16x8*)(ktb + (size_t)(c0+lr)*NM + j0 + lg*8);
        #pragma unroll
        for (int t=0;t<16;++t){
            bf16x8 bfr = *(const bf16x8*)(ktb + (size_t)(t*16+lr)*NM + j0 + lg*8);
            acc[t] = MFMA(af, bfr, acc[t]);
        }
    }
    #pragma unroll
    for (int t=0;t<16;++t){
        #pragma unroll
        for (int r=0;r<4;++r){
            int c  = c0 + 4*lg + r;
            int cp = t*16 + lr;
            gpart[(((size_t)jc*4 + b)*256 + c)*256 + cp] = acc[t][r];
        }
    }
}

// ---------------- K2c: reduce 8 Gram partials -> bf16 G. GRID 1024 ----------------
__global__ __launch_bounds__(256) void gfin_kernel(
    const float* __restrict__ gpart, bf16* __restrict__ gbf)
{
    int gid = blockIdx.x*256 + threadIdx.x;
    int b = gid>>16, idx = gid&65535;
    float s = 0.0f;
    #pragma unroll
    for (int jc=0;jc<8;++jc) s += gpart[((size_t)jc*4 + b)*65536 + idx];
    gbf[(size_t)b*65536 + idx] = (bf16)s;
}

// ---------------- K2d: per-row stats via Y = Q.G. GRID 256 ----------------
__global__ __launch_bounds__(256) void rowstats_kernel(
    const bf16* __restrict__ q, const bf16* __restrict__ gbf,
    const float* __restrict__ ksumg, float* __restrict__ stats)
{
    __shared__ float ksum[256];
    const int wave = threadIdx.x>>6, lane = threadIdx.x&63;
    const int lr = lane&15, lg = lane>>4;
    const int n0 = blockIdx.x*64;
    const int b = n0 / NQ;
    const int row16 = n0 + wave*16;
    ksum[threadIdx.x] = ksumg[b*256 + threadIdx.x];
    __syncthreads();

    bf16x8 qf[8];
    const bf16* qr = q + (size_t)(row16+lr)*CD + lg*8;
    #pragma unroll
    for (int ch=0; ch<8; ++ch) qf[ch] = *(const bf16x8*)(qr + ch*32);

    const bf16* gb = gbf + (size_t)b*65536;
    f32x4 acc[16];
    #pragma unroll
    for (int t=0;t<16;++t) acc[t]=(f32x4){0,0,0,0};
    #pragma unroll
    for (int t=0;t<16;++t){
        #pragma unroll
        for (int ch=0; ch<8; ++ch){
            bf16x8 bf = *(const bf16x8*)&gb[(size_t)(t*16+lr)*256 + ch*32 + lg*8];
            acc[t] = MFMA(qf[ch], bf, acc[t]);
        }
    }
    float msq[4]={0,0,0,0}, mean[4]={0,0,0,0};
    #pragma unroll
    for (int t=0;t<16;++t){
        float ks = ksum[t*16+lr];
        #pragma unroll
        for (int r=0;r<4;++r){
            float qv = (float)q[(size_t)(row16+4*lg+r)*CD + t*16+lr];
            msq[r]  = fmaf(acc[t][r], qv, msq[r]);
            mean[r] = fmaf(qv, ks, mean[r]);
        }
    }
    #pragma unroll
    for (int off=1; off<16; off<<=1){
        #pragma unroll
        for (int r=0;r<4;++r){
            msq[r]  += __shfl_xor(msq[r], off);
            mean[r] += __shfl_xor(mean[r], off);
        }
    }
    if (lr==0){
        #pragma unroll
        for (int r=0;r<4;++r){
            int row = row16 + 4*lg + r;
            float mu = mean[r]*(1.0f/NM);
            float ms = msq[r]*(1.0f/NM);
            float var = ms - mu*mu;
            float rstd = rsqrtf(fmaxf(var,0.0f) + 1e-5f);
            float a2 = rstd * (1.0f/16.0f) * 1.4426950408889634f;
            stats[row*2+0] = mu*a2;   // c2
            stats[row*2+1] = a2;
        }
    }
}

// ---------------- K3: flash — Q-tile 128, DOUBLE-BUFFERED K+P, ONE barrier/tile ----------------
// GRID 512 (qt*4+slice) x 512 threads. Region after each barrier = PV_t || QK_{t+1}:
// independent MFMA chains interleave; exp-VALU overlaps PV-MFMA.
// Race audit: K buf b written at iter-t top (tile t+1, b=(t+1)&1) — last read by QK_{t-1}
//   (same buf), which completed before barrier(t-1) < write. P buf (t+1)&1 written by
//   QK_{t+1} (after barrier(t)) — last read by PV_{t-1} (before barrier(t)). All safe.
__global__ __launch_bounds__(512) void flash_kernel(
    const bf16* __restrict__ q, const bf16* __restrict__ k,
    const bf16* __restrict__ vt, const float* __restrict__ stats,
    bf16* __restrict__ opart, float* __restrict__ dpart)
{
    __shared__ __align__(16) bf16 K_lds[2][64][264];   // 67.6 KB
    __shared__ __align__(16) bf16 P_lds[2][128][72];   // 36.9 KB
    const int wave = threadIdx.x>>6, lane = threadIdx.x&63;
    const int lr = lane&15, lg = lane>>4;
    const int qt = blockIdx.x>>2, slice = blockIdx.x&3;
    const int n0 = qt*128;
    const int b = n0 / NQ;
    const bf16* kb = k  + (size_t)b*NM*CD;
    const bf16* vb = vt + (size_t)b*CD*NM + (size_t)(wave*32)*NM;
    const int row16 = n0 + wave*16;

    bf16x8 qf[8];
    const bf16* qr = q + (size_t)(row16+lr)*CD + lg*8;
    #pragma unroll
    for (int ch=0; ch<8; ++ch) qf[ch] = *(const bf16x8*)(qr + ch*32);

    float c2r[4], a2r[4];
    #pragma unroll
    for (int r=0;r<4;++r){
        int row = row16 + 4*lg + r;
        c2r[r] = stats[row*2+0];
        a2r[r] = stats[row*2+1];
    }

    f32x4 oacc[8][2];
    #pragma unroll
    for (int rt=0;rt<8;++rt){ oacc[rt][0]=(f32x4){0,0,0,0}; oacc[rt][1]=(f32x4){0,0,0,0}; }
    float denom[4]={0,0,0,0};

    const int jbeg = slice*(NM/4);
    bf16x8 kreg[4];

#define LOADK(JJ) { _Pragma("unroll") \
    for (int p=0;p<4;++p){ int f = threadIdx.x + p*512; \
        kreg[p] = *(const bf16x8*)(kb + (size_t)((JJ) + (f>>5))*CD + (f&31)*8); } }
#define WRITEK(BB) { _Pragma("unroll") \
    for (int p=0;p<4;++p){ int f = threadIdx.x + p*512; \
        *(bf16x8*)&K_lds[BB][f>>5][(f&31)*8] = kreg[p]; } }
#define QK(BB) { \
    f32x4 s0=(f32x4){0,0,0,0}, s1=(f32x4){0,0,0,0}; \
    f32x4 s2=(f32x4){0,0,0,0}, s3=(f32x4){0,0,0,0}; \
    _Pragma("unroll") \
    for (int ch=0; ch<8; ++ch){ \
        s0 = MFMA(qf[ch], *(const bf16x8*)&K_lds[BB][     lr][lg*8+ch*32], s0); \
        s1 = MFMA(qf[ch], *(const bf16x8*)&K_lds[BB][16+lr][lg*8+ch*32], s1); \
        s2 = MFMA(qf[ch], *(const bf16x8*)&K_lds[BB][32+lr][lg*8+ch*32], s2); \
        s3 = MFMA(qf[ch], *(const bf16x8*)&K_lds[BB][48+lr][lg*8+ch*32], s3); \
    } \
    _Pragma("unroll") \
    for (int r=0;r<4;++r){ \
        float p0 = exp2f(s0[r]*a2r[r] - c2r[r]); \
        float p1 = exp2f(s1[r]*a2r[r] - c2r[r]); \
        float p2 = exp2f(s2[r]*a2r[r] - c2r[r]); \
        float p3 = exp2f(s3[r]*a2r[r] - c2r[r]); \
        denom[r] += (p0 + p1) + (p2 + p3); \
        int prow = wave*16 + 4*lg + r; \
        P_lds[BB][prow][lr]    = (bf16)p0; \
        P_lds[BB][prow][16+lr] = (bf16)p1; \
        P_lds[BB][prow][32+lr] = (bf16)p2; \
        P_lds[BB][prow][48+lr] = (bf16)p3; \
    } }
#define PV(BB, J0) { _Pragma("unroll") \
    for (int w=0; w<2; ++w){ \
        bf16x8 vf0 = *(const bf16x8*)(vb + (size_t)lr*NM      + (J0) + w*32 + lg*8); \
        bf16x8 vf1 = *(const bf16x8*)(vb + (size_t)(16+lr)*NM + (J0) + w*32 + lg*8); \
        _Pragma("unroll") \
        for (int rt=0;rt<8;++rt){ \
            bf16x8 pf = *(const bf16x8*)&P_lds[BB][rt*16+lr][w*32+lg*8]; \
            oacc[rt][0] = MFMA(pf, vf0, oacc[rt][0]); \
            oacc[rt][1] = MFMA(pf, vf1, oacc[rt][1]); \
        } } }

    // prologue
    LOADK(jbeg);
    WRITEK(0);
    __syncthreads();
    QK(0);                // P[0] from tile 0
    LOADK(jbeg + 64);     // kreg <- tile 1

    for (int t=0; t<16; ++t){
        const int j0 = jbeg + t*64;
        if (t < 15) WRITEK((t+1)&1);      // K[t+1] into other buffer
        __syncthreads();                  // P[t] + K[t+1] now visible to all
        PV(t&1, j0);                      // consume P[t], V tile t
        if (t < 15){
            if (t < 14) LOADK(jbeg + (t+2)*64);   // prefetch tile t+2
            QK((t+1)&1);                  // P[t+1] from K[t+1]
        }
    }
#undef LOADK
#undef WRITEK
#undef QK
#undef PV

    #pragma unroll
    for (int off=1; off<16; off<<=1){
        #pragma unroll
        for (int r=0;r<4;++r) denom[r] += __shfl_xor(denom[r], off);
    }
    if (lr==0){
        #pragma unroll
        for (int r=0;r<4;++r)
            dpart[(size_t)slice*NTOT + row16 + 4*lg + r] = denom[r];
    }
    #pragma unroll
    for (int rt=0;rt<8;++rt){
        #pragma unroll
        for (int ct=0;ct<2;++ct){
            #pragma unroll
            for (int r=0;r<4;++r){
                int row = n0 + rt*16 + 4*lg + r;
                int co  = wave*32 + ct*16 + lr;
                opart[((size_t)slice*NTOT + row)*CD + co] = (bf16)oacc[rt][ct][r];
            }
        }
    }
}

// ---------------- K3b: dinv[row] = 1/sum_s dpart[s][row]. GRID 64 ----------------
__global__ __launch_bounds__(256) void dinv_kernel(
    const float* __restrict__ dpart, float* __restrict__ dinv)
{
    int row = blockIdx.x*256 + threadIdx.x;
    dinv[row] = 1.0f / (dpart[row] + dpart[NTOT+row]
                      + dpart[2*(size_t)NTOT+row] + dpart[3*(size_t)NTOT+row]);
}

// ---------------- K4: fused combine + final projection. GRID 1024 ----------------
// Same XCD-friendly split as proj: rowblk low bits, co high bits.
__global__ __launch_bounds__(256) void final_kernel(
    const bf16* __restrict__ opart, const float* __restrict__ dinv,
    const float* __restrict__ query, const bf16* __restrict__ W,
    const float* __restrict__ bias, float* __restrict__ out)
{
    const int wave = threadIdx.x>>6, lane = threadIdx.x&63;
    const int lr = lane&15, lg = lane>>4;
    const int n0 = (blockIdx.x & 255)*64 + wave*16;
    const int co0 = (blockIdx.x >> 8)*64;
    const int n = n0 + lr;
    const float di = dinv[n];

    bf16x8 uf[8];
    #pragma unroll
    for (int ch=0; ch<8; ++ch){
        const int c = lg*8 + ch*32;
        float a[8];
        f32x4 qa = *(const f32x4*)(query + (size_t)n*CD + c);
        f32x4 qb = *(const f32x4*)(query + (size_t)n*CD + c + 4);
        #pragma unroll
        for (int e=0;e<4;++e){ a[e]=qa[e]; a[4+e]=qb[e]; }
        #pragma unroll
        for (int s=0;s<4;++s){
            bf16x8 o = *(const bf16x8*)&opart[((size_t)s*NTOT + n)*CD + c];
            #pragma unroll
            for (int e=0;e<8;++e) a[e] = fmaf((float)o[e], di, a[e]);
        }
        bf16x8 t;
        #pragma unroll
        for (int e=0;e<8;++e) t[e] = (bf16)a[e];
        uf[ch] = t;
    }

    f32x4 acc[4];
    #pragma unroll
    for (int t=0;t<4;++t) acc[t]=(f32x4){0,0,0,0};
    #pragma unroll
    for (int t=0;t<4;++t){
        const bf16* wr = W + (size_t)(co0+t*16+lr)*CD + lg*8;
        #pragma unroll
        for (int ch=0; ch<8; ++ch)
            acc[t] = MFMA(*(const bf16x8*)(wr+ch*32), uf[ch], acc[t]);
    }
    #pragma unroll
    for (int t=0;t<4;++t){
        int co = co0 + t*16 + 4*lg;
        f32x4 o;
        #pragma unroll
        for (int r=0;r<4;++r) o[r] = acc[t][r] + bias[co+r];
        *(f32x4*)(out + (size_t)n*CD + co) = o;
    }
}

extern "C" void kernel_launch(void* const* d_in, const int* in_sizes, int n_in,
                              void* d_out, int out_size, void* d_ws, size_t ws_size,
                              hipStream_t stream)
{
    const float* query = (const float*)d_in[0];
    const float* key_  = (const float*)d_in[1];
    const float* value = (const float*)d_in[2];
    const float* Wq = (const float*)d_in[3];
    const float* bq = (const float*)d_in[4];
    const float* Wk = (const float*)d_in[5];
    const float* bk = (const float*)d_in[6];
    const float* Wv = (const float*)d_in[7];
    const float* bv = (const float*)d_in[8];
    const float* Wm = (const float*)d_in[9];
    const float* bm = (const float*)d_in[10];
    float* out = (float*)d_out;

    bf16* wsb = (bf16*)d_ws;
    bf16* wqb = wsb;                                    // 4 x 65536 bf16 weights
    bf16* wkb = wqb + 65536;
    bf16* wvb = wkb + 65536;
    bf16* wmb = wvb + 65536;
    bf16* qbuf  = wsb + 4*65536;                        // [NTOT][256] bf16
    bf16* kbuf  = qbuf  + (size_t)NTOT*CD;              // [NTOT][256] bf16
    bf16* vtbuf = kbuf  + (size_t)NTOT*CD;              // [B][256][NM] bf16
    float* statsbuf = (float*)(vtbuf + (size_t)NTOT*CD);// [NTOT][2] = {c2, a2}
    float* ksumbuf  = statsbuf + (size_t)NTOT*2;        // [4][256]
    float* dinvbuf  = ksumbuf + 1024;                   // [NTOT]
    bf16*  gbf      = (bf16*)(dinvbuf + NTOT);          // [4][256][256] bf16
    float* dpart    = (float*)(gbf + (size_t)4*65536);  // [4][NTOT]
    bf16*  opart    = (bf16*)(dpart + (size_t)NTOT*4);  // [4][NTOT][256] bf16 (32 MB)
    bf16*  ktbuf    = opart;                            // ALIAS: Kt [B][256][NM], dead before flash
    float* gpart    = (float*)(opart + (size_t)4*NTOT*CD); // [8][4][256][256] f32 (8 MB)

    cvt_w_kernel<<<64,256,0,stream>>>(Wq, Wk, Wv, Wm, wsb);
    proj_kernel<0><<<1024,256,0,stream>>>(query, wqb, bq, qbuf,  nullptr);
    proj_kernel<2><<<1024,256,0,stream>>>(key_,  wkb, bk, kbuf,  ktbuf);   // kbuf + Kt in one pass
    proj_kernel<1><<<1024,256,0,stream>>>(value, wvb, bv, nullptr, vtbuf);
    ksum_kernel<<<256,256,0,stream>>>(ktbuf, ksumbuf);
    gram_kernel<<<128,256,0,stream>>>(ktbuf, gpart);
    gfin_kernel<<<1024,256,0,stream>>>(gpart, gbf);
    rowstats_kernel<<<256,256,0,stream>>>(qbuf, gbf, ksumbuf, statsbuf);
    flash_kernel<<<512,512,0,stream>>>(qbuf, kbuf, vtbuf, statsbuf, opart, dpart); // clobbers ktbuf (dead)
    dinv_kernel<<<64,256,0,stream>>>(dpart, dinvbuf);
    final_kernel<<<1024,256,0,stream>>>(opart, dinvbuf, query, wmb, bm, out);
}